// Round 9
// baseline (2244.971 us; speedup 1.0000x reference)
//
#include <hip/hip_runtime.h>
#include <cstdio>

// ---------------------------------------------------------------------------
// GraphMessagePassing, float32 end-to-end (reference uses jnp.float32 + int32
// edge_index). Wave-per-edge / wave-per-node; lane j owns output channel j.
// ---------------------------------------------------------------------------

__global__ void zero_ws(float* __restrict__ p, int n) {
    int i = blockIdx.x * blockDim.x + threadIdx.x;
    if (i < n) p[i] = 0.0f;
}

// Edge phase: h = relu(b1 + [node[src], edge_feat] @ w1); m = b2 + relu(h) @ w2
// then atomicAdd of m into agg[dst].
__global__ void GraphMessagePassing_5952824672257_kernel(
    const float* __restrict__ nodef,   // [N,64]
    const float* __restrict__ edgef,   // [E,16]
    const int*   __restrict__ eidx,    // [2,E]: src row then dst row (int32)
    const float* __restrict__ w1,      // [80,64] row-major
    const float* __restrict__ b1,      // [64]
    const float* __restrict__ w2,      // [64,64]
    const float* __restrict__ b2,      // [64]
    float* __restrict__ agg,           // [N,64] f32, pre-zeroed
    int n_edges, int n_nodes)
{
    const int lane = threadIdx.x & 63;
    const int e = (blockIdx.x * blockDim.x + threadIdx.x) >> 6;  // wave id
    if (e >= n_edges) return;

    int d = eidx[n_edges + e];
    if (d < 0 || d >= n_nodes) return;   // safety
    int s = eidx[e];
    if (s < 0 || s >= n_nodes) s = 0;    // safety clamp

    float h = b1[lane];
    const float* xs = nodef + (size_t)s * 64;
    for (int k = 0; k < 64; ++k)
        h = fmaf(xs[k], w1[k * 64 + lane], h);
    const float* xe = edgef + (size_t)e * 16;
    for (int k = 0; k < 16; ++k)
        h = fmaf(xe[k], w1[(64 + k) * 64 + lane], h);
    h = fmaxf(h, 0.0f);

    float m = b2[lane];
    for (int t = 0; t < 64; ++t) {
        float ht = __shfl(h, t, 64);
        m = fmaf(ht, w2[t * 64 + lane], m);
    }

    atomicAdd(agg + (size_t)d * 64 + lane, m);
}

// Node phase: out = relu(b1 + [node, agg] @ w_u1) @ w_u2 + b_u2, f32 out.
__global__ void node_mlp_wave(
    const float* __restrict__ nodef,   // [N,64]
    const float* __restrict__ agg,     // [N,64]
    const float* __restrict__ w1,      // [128,64]
    const float* __restrict__ b1,      // [64]
    const float* __restrict__ w2,      // [64,64]
    const float* __restrict__ b2,      // [64]
    float* __restrict__ out,           // [N,64] f32
    int n_nodes)
{
    const int lane = threadIdx.x & 63;
    const int n = (blockIdx.x * blockDim.x + threadIdx.x) >> 6;
    if (n >= n_nodes) return;

    float h = b1[lane];
    const float* xs = nodef + (size_t)n * 64;
    for (int k = 0; k < 64; ++k)
        h = fmaf(xs[k], w1[k * 64 + lane], h);
    const float* xa = agg + (size_t)n * 64;
    for (int k = 0; k < 64; ++k)
        h = fmaf(xa[k], w1[(64 + k) * 64 + lane], h);
    h = fmaxf(h, 0.0f);

    float m = b2[lane];
    for (int t = 0; t < 64; ++t) {
        float ht = __shfl(h, t, 64);
        m = fmaf(ht, w2[t * 64 + lane], m);
    }

    out[(size_t)n * 64 + lane] = m;   // full-coverage f32 store
}

extern "C" void kernel_launch(void* const* d_in, const int* in_sizes, int n_in,
                              void* d_out, int out_size, void* d_ws, size_t ws_size,
                              hipStream_t stream) {
    // Documented setup_inputs() order (confirmed by round-8 size dump):
    // 0 node_features[N,64] f32, 1 edge_features[E,16] f32, 2 edge_index[2,E] i32,
    // 3 w_m1[80,64], 4 b_m1, 5 w_m2[64,64], 6 b_m2,
    // 7 w_u1[128,64], 8 b_u1, 9 w_u2[64,64], 10 b_u2   (all f32)
    const float* nodef = (const float*)d_in[0];
    const float* edgef = (const float*)d_in[1];
    const int*   eidx  = (const int*)d_in[2];
    const float* w_m1  = (const float*)d_in[3];
    const float* b_m1  = (const float*)d_in[4];
    const float* w_m2  = (const float*)d_in[5];
    const float* b_m2  = (const float*)d_in[6];
    const float* w_u1  = (const float*)d_in[7];
    const float* b_u1  = (const float*)d_in[8];
    const float* w_u2  = (const float*)d_in[9];
    const float* b_u2  = (const float*)d_in[10];
    float* out = (float*)d_out;

    const int n_nodes = out_size / 64;
    const int n_edges = in_sizes[2] / 2;

    fprintf(stderr, "[KL] f32 pipeline E=%d N=%d out_size=%d ws=%zu\n",
            n_edges, n_nodes, out_size, ws_size);
    fflush(stderr);

    const int threads = 256;

    // agg[N,64] f32 in workspace (needs 12.8 MB; ws is 320 MB).
    float* agg = (float*)d_ws;
    const int zn = n_nodes * 64;
    zero_ws<<<(zn + threads - 1) / threads, threads, 0, stream>>>(agg, zn);

    const long edge_threads = (long)n_edges * 64;
    GraphMessagePassing_5952824672257_kernel<<<
        (int)((edge_threads + threads - 1) / threads), threads, 0, stream>>>(
        nodef, edgef, eidx, w_m1, b_m1, w_m2, b_m2, agg, n_edges, n_nodes);

    const long node_threads = (long)n_nodes * 64;
    node_mlp_wave<<<
        (int)((node_threads + threads - 1) / threads), threads, 0, stream>>>(
        nodef, agg, w_u1, b_u1, w_u2, b_u2, out, n_nodes);

    hipError_t le = hipGetLastError();
    fprintf(stderr, "[KL] last=%d(%s)\n", (int)le, hipGetErrorName(le));
    fflush(stderr);
}